// Round 7
// baseline (855.824 us; speedup 1.0000x reference)
//
#include <hip/hip_runtime.h>
#include <math.h>

#define DD 256
#define KK 1024
#define TT 4096
#define BB 16
#define NN (BB*TT)            // 65536
#define QSZ (BB*DD*TT)        // 16777216
#define LOSS_POS QSZ
#define IDX_OFF (QSZ+1)
#define PERP_POS (QSZ+1+NN)

// ws layout
#define WS_NE    0                   // K f32
#define WS_IDX   4096                // N int
#define WS_CNT   (4096 + NN*4)       // K int    (zeroed)
#define WS_LOSS  (WS_CNT + KK*4)     // double   (zeroed)
#define WS_FLAG  (WS_LOSS + 8)       // int      (zeroed)

// scratch carved out of q_out region (consumed before vq_gather overwrites)
#define OUT_EH   0                   // K*D fp16 (512 KB)
#define OUT_XN   (1u<<20)            // N f32    (256 KB)
#define OUT_FL   (2u<<20)            // N int    (256 KB)

#define THR 1.4e-4f

typedef __attribute__((ext_vector_type(8))) _Float16 half8v;
typedef __attribute__((ext_vector_type(4))) float f32x4;

#define GLOAD16(gp, lp) __builtin_amdgcn_global_load_lds( \
    (const __attribute__((address_space(1))) unsigned int*)(gp), \
    (__attribute__((address_space(3))) unsigned int*)(lp), 16, 0, 0)

__device__ __forceinline__ unsigned mapf(float f) {   // order-preserving f32->u32
    unsigned b = __float_as_uint(f);
    return (b & 0x80000000u) ? ~b : (b | 0x80000000u);
}

// ---- numpy-exact pairwise sum of squares over 256 elements ----
__device__ __forceinline__ float np_pairwise_sq(const float* __restrict__ p,
                                                const long stride) {
    float tot[2];
    #pragma unroll
    for (int h = 0; h < 2; ++h) {
        const float* q = p + (long)h * 128 * stride;
        float r[8];
        #pragma unroll
        for (int j = 0; j < 8; ++j) {
            const float v = q[(long)j * stride];
            r[j] = __fmul_rn(v, v);
        }
        for (int i = 8; i < 128; i += 8) {
            #pragma unroll
            for (int j = 0; j < 8; ++j) {
                const float v = q[(long)(i + j) * stride];
                r[j] = __fadd_rn(r[j], __fmul_rn(v, v));
            }
        }
        tot[h] = __fadd_rn(__fadd_rn(__fadd_rn(r[0], r[1]), __fadd_rn(r[2], r[3])),
                           __fadd_rn(__fadd_rn(r[4], r[5]), __fadd_rn(r[6], r[7])));
    }
    return __fadd_rn(tot[0], tot[1]);
}

// ---------------- prep: ||e||^2 + eh = fp16(1024*e) ----------------
__global__ __launch_bounds__(256) void vq_prep_e(const float* __restrict__ emb,
                                                 float* __restrict__ ne,
                                                 _Float16* __restrict__ eh) {
    const int k = blockIdx.x * 256 + threadIdx.x;
    const float* row = emb + (size_t)k * DD;
    ne[k] = np_pairwise_sq(row, 1);
    _Float16* er = eh + (size_t)k * DD;
    #pragma unroll 4
    for (int c = 0; c < DD / 8; ++c) {
        half8v h;
        #pragma unroll
        for (int j = 0; j < 8; ++j) h[j] = (_Float16)(row[c * 8 + j] * 1024.0f);
        *reinterpret_cast<half8v*>(er + c * 8) = h;
    }
}

// ---------------- ||x||^2 (np-exact) ----------------
__global__ __launch_bounds__(256) void vq_xnorm(const float* __restrict__ x,
                                                float* __restrict__ xn) {
    const int n = blockIdx.x * 256 + threadIdx.x;
    const int b = n >> 12;
    const int t = n & 4095;
    xn[n] = np_pairwise_sq(x + (size_t)b * DD * TT + t, TT);
}

// ---------------- main: fp16-MFMA scores + top-2 fold + flag ----------------
// grid 1024 (t-tile 64). 4 waves x 16 t each; full K=1024; d-chunks 32.
// Per-wave regs: Bf 32 VGPR + acc 32 AGPR -> ~5 waves/SIMD; 4 blocks/CU grid.
__global__ __launch_bounds__(256) void vq_argmin_f16(
    const float* __restrict__ x,
    const _Float16* __restrict__ eh,
    const float* __restrict__ ne,
    const float* __restrict__ xn,
    int* __restrict__ out_idx,
    int* __restrict__ flag_cnt,
    int* __restrict__ flag_list)
{
    __shared__ __align__(16) _Float16 Elds[2][128 * 32];  // 2 x 8 KB
    __shared__ float nes[KK];                             // 4 KB

    const int tid = threadIdx.x;
    const int w   = tid >> 6;
    const int l   = tid & 63;
    const int l15 = l & 15;
    const int lg  = l >> 4;
    const int bx  = blockIdx.x;        // 1024
    const int b   = bx >> 6;           // 0..15
    const int t0  = (bx & 63) * 64;
    const int tw0 = t0 + w * 16;

    for (int i = tid; i < KK; i += 256) nes[i] = ne[i];

    // B fragment: 16 t-columns of x -> fp16 registers (one frag per wave)
    half8v Bf[8];
    const float* xb = x + (size_t)b * DD * TT;
    {
        const int t = tw0 + l15;
        #pragma unroll
        for (int dc = 0; dc < 8; ++dc) {
            const int d0 = dc * 32 + lg * 8;
            half8v v;
            #pragma unroll
            for (int j = 0; j < 8; ++j) v[j] = (_Float16)xb[(size_t)(d0 + j) * TT + t];
            Bf[dc] = v;
        }
    }
    const float xnv = xn[b * TT + tw0 + l15];

    float v1 = 3.4028235e38f, v2 = 3.4028235e38f;
    int   k1 = 0;

    // staging: thread tid covers LDS bytes tid*16 (rows 0-63) and +4096 (rows 64-127)
    const int row0 = tid >> 2;                    // 0..63
    const int cg   = tid & 3;
    const int xc   = cg ^ ((row0 >> 1) & 3);      // source-chunk swizzle (involution)
    _Float16* lds0[2] = { &Elds[0][w * 512], &Elds[1][w * 512] };
    _Float16* lds1[2] = { &Elds[0][2048 + w * 512], &Elds[1][2048 + w * 512] };

    // prologue: stage step 0 into buf 0
    GLOAD16(eh + (size_t)row0 * DD + xc * 8, lds0[0]);
    GLOAD16(eh + (size_t)(row0 + 64) * DD + xc * 8, lds1[0]);
    __syncthreads();

    f32x4 acc[8];
    const int rsw = (lg ^ ((l15 >> 1) & 3)) * 8;  // read-side swizzle

    for (int s = 0; s < 64; ++s) {
        const int kc = s >> 3, dc = s & 7;

        if (dc == 0) {
            #pragma unroll
            for (int fk = 0; fk < 8; ++fk) acc[fk] = f32x4{0.f, 0.f, 0.f, 0.f};
        }

        // issue next-step loads directly to the other LDS buffer
        if (s + 1 < 64) {
            const int kn = (s + 1) >> 3, dn = (s + 1) & 7;
            const _Float16* src = eh + (size_t)(kn * 128 + row0) * DD + dn * 32 + xc * 8;
            GLOAD16(src, lds0[(s + 1) & 1]);
            GLOAD16(src + (size_t)64 * DD, lds1[(s + 1) & 1]);
        }

        {
            const _Float16* ebuf = Elds[s & 1];
            #pragma unroll
            for (int fk = 0; fk < 8; ++fk) {
                const half8v Af = *(const half8v*)&ebuf[(fk * 16 + l15) * 32 + rsw];
                acc[fk] = __builtin_amdgcn_mfma_f32_16x16x32_f16(Af, Bf[dc], acc[fk], 0, 0, 0);
            }
        }

        if (dc == 7) {
            #pragma unroll
            for (int fk = 0; fk < 8; ++fk) {
                const float4 nev = *reinterpret_cast<const float4*>(
                    &nes[kc * 128 + fk * 16 + lg * 4]);
                const float nv[4] = {nev.x, nev.y, nev.z, nev.w};
                #pragma unroll
                for (int r = 0; r < 4; ++r) {
                    const float sa = __fadd_rn(xnv, nv[r]);
                    // dot' = 1024*dot  ->  score = sa - 2^-9 * dot'
                    const float sc = fmaf(-0.001953125f, acc[fk][r], sa);
                    const float mx = fmaxf(v1, sc);
                    v2 = fminf(v2, mx);
                    const bool c = sc < v1;
                    v1 = c ? sc : v1;
                    k1 = c ? (kc * 128 + fk * 16 + lg * 4 + r) : k1;
                }
            }
        }

        // single barrier per step: compiler drains vmcnt(0)+lgkmcnt(0) before
        // s_barrier -> next-step loads landed AND all waves done reading buf.
        __syncthreads();
    }

    // cross-lane merge over lg groups (k-partition), then write + flag
    #pragma unroll
    for (int m = 16; m <= 32; m <<= 1) {
        const float ov1 = __shfl_xor(v1, m);
        const float ov2 = __shfl_xor(v2, m);
        const int   ok1 = __shfl_xor(k1, m);
        const float mx  = fmaxf(v1, ov1);
        v2 = fminf(fminf(v2, ov2), mx);
        const bool take = (ov1 < v1) || (ov1 == v1 && ok1 < k1);
        v1 = take ? ov1 : v1;
        k1 = take ? ok1 : k1;
    }
    if (l < 16) {
        const int n = b * TT + tw0 + l15;
        out_idx[n] = k1;
        if (v2 - v1 <= THR) {
            const int p = atomicAdd(flag_cnt, 1);
            flag_list[p] = n;
        }
    }
}

// ---------------- cleanup: exact fp32 rescore of flagged rows ----------------
#define CR 16
__global__ __launch_bounds__(512) void vq_cleanup(
    const float* __restrict__ x, const float* __restrict__ emb,
    const float* __restrict__ ne, const float* __restrict__ xn,
    const int* __restrict__ flag_cnt, const int* __restrict__ flag_list,
    int* __restrict__ out_idx)
{
    __shared__ float xr[CR][DD + 4];
    __shared__ float xns_s[CR];
    __shared__ int rowid[CR];
    __shared__ unsigned long long wred[8][8];

    const int tid = threadIdx.x;
    const int wv  = tid >> 6, l = tid & 63;
    const int kt  = tid & 255;
    const int rt  = tid >> 8;
    const int cnt = *flag_cnt;

    for (int base = blockIdx.x * CR; base < cnt; base += gridDim.x * CR) {
        const int nr = min(CR, cnt - base);
        __syncthreads();
        if (tid < CR) {
            const int n = flag_list[base + ((tid < nr) ? tid : (nr - 1))];
            rowid[tid] = n;
            xns_s[tid] = xn[n];
        }
        __syncthreads();
        {
            const int r = tid >> 5, d0 = (tid & 31) * 8;
            const int n = rowid[r], bb2 = n >> 12, t = n & 4095;
            const float* xc = x + (size_t)bb2 * DD * TT + t;
            #pragma unroll
            for (int q = 0; q < 8; ++q) xr[r][d0 + q] = xc[(size_t)(d0 + q) * TT];
        }
        __syncthreads();

        const int k0 = kt * 4;
        float acc4[4][8];
        #pragma unroll
        for (int a = 0; a < 4; ++a)
            #pragma unroll
            for (int r = 0; r < 8; ++r) acc4[a][r] = 0.f;

        for (int ch = 0; ch < DD / 8; ++ch) {
            const int d0 = ch * 8;
            float xc8[8][8];
            #pragma unroll
            for (int r = 0; r < 8; ++r) {
                const float4 xa = *reinterpret_cast<const float4*>(&xr[rt * 8 + r][d0]);
                const float4 xbv = *reinterpret_cast<const float4*>(&xr[rt * 8 + r][d0 + 4]);
                xc8[r][0] = xa.x;  xc8[r][1] = xa.y;  xc8[r][2] = xa.z;  xc8[r][3] = xa.w;
                xc8[r][4] = xbv.x; xc8[r][5] = xbv.y; xc8[r][6] = xbv.z; xc8[r][7] = xbv.w;
            }
            #pragma unroll
            for (int a = 0; a < 4; ++a) {
                const float* er = emb + (size_t)(k0 + a) * DD + d0;
                const float4 ea = *reinterpret_cast<const float4*>(er);
                const float4 eb2 = *reinterpret_cast<const float4*>(er + 4);
                const float ev[8] = {ea.x, ea.y, ea.z, ea.w, eb2.x, eb2.y, eb2.z, eb2.w};
                #pragma unroll
                for (int q = 0; q < 8; ++q)
                    #pragma unroll
                    for (int r = 0; r < 8; ++r)
                        acc4[a][r] = fmaf(ev[q], xc8[r][q], acc4[a][r]);
            }
        }

        #pragma unroll
        for (int r = 0; r < 8; ++r) {
            const float xnv2 = xns_s[rt * 8 + r];
            unsigned long long bb3 = ~0ull;
            #pragma unroll
            for (int a = 0; a < 4; ++a) {
                const float s1 = __fadd_rn(xnv2, ne[k0 + a]);
                const float sc = __fsub_rn(s1, __fmul_rn(2.0f, acc4[a][r]));
                const unsigned long long pkk =
                    ((unsigned long long)mapf(sc) << 32) | (unsigned)(k0 + a);
                bb3 = (pkk < bb3) ? pkk : bb3;
            }
            unsigned long long v = bb3;
            #pragma unroll
            for (int m = 1; m < 64; m <<= 1) {
                const unsigned long long o = __shfl_xor(v, m);
                v = (o < v) ? o : v;
            }
            if (l == 0) wred[wv][r] = v;
        }
        __syncthreads();
        if (wv == 0) {
            const int row = l >> 2, sw = l & 3;
            const int srcw = (row < 8) ? sw : (4 + sw);
            unsigned long long v = wred[srcw][row & 7];
            #pragma unroll
            for (int m = 1; m < 4; m <<= 1) {
                const unsigned long long o = __shfl_xor(v, m);
                v = (o < v) ? o : v;
            }
            if (sw == 0 && row < nr) out_idx[rowid[row]] = (int)(v & 0xFFFFFFFFu);
        }
    }
}

// ---------------- gather (16B/lane) + loss + counts ----------------
// grid 512: (gblk 0..63, dslice 0..7); thread = 4 consecutive t, 32 d
__global__ __launch_bounds__(256) void vq_gather(
    const float* __restrict__ x, const float* __restrict__ emb,
    const int* __restrict__ idx, float* __restrict__ out,
    int* __restrict__ counts, double* __restrict__ loss_acc)
{
    const int tid = threadIdx.x;
    const int bid = blockIdx.x;
    const int ds2 = bid & 7;
    const int g   = (bid >> 3) * 256 + tid;    // 0..16383
    const int b   = g >> 10;
    const int t0q = (g & 1023) * 4;
    const int n0  = b * TT + t0q;

    int ids[4];
    #pragma unroll
    for (int q = 0; q < 4; ++q) ids[q] = idx[n0 + q];

    const int dbase = ds2 * 32;
    const float* xb = x + (size_t)b * DD * TT;
    float* ob       = out + (size_t)b * DD * TT;

    float s = 0.f;
    for (int d4 = 0; d4 < 8; ++d4) {
        const int d = dbase + d4 * 4;
        float ea[4][4];
        #pragma unroll
        for (int q = 0; q < 4; ++q) {
            const float4 v = *reinterpret_cast<const float4*>(emb + (size_t)ids[q] * DD + d);
            ea[q][0] = v.x; ea[q][1] = v.y; ea[q][2] = v.z; ea[q][3] = v.w;
        }
        #pragma unroll
        for (int di = 0; di < 4; ++di) {
            const float4 xv = *reinterpret_cast<const float4*>(xb + (size_t)(d + di) * TT + t0q);
            float4 ov;
            ov.x = ea[0][di]; ov.y = ea[1][di]; ov.z = ea[2][di]; ov.w = ea[3][di];
            *reinterpret_cast<float4*>(ob + (size_t)(d + di) * TT + t0q) = ov;
            float df;
            df = ov.x - xv.x; s = fmaf(df, df, s);
            df = ov.y - xv.y; s = fmaf(df, df, s);
            df = ov.z - xv.z; s = fmaf(df, df, s);
            df = ov.w - xv.w; s = fmaf(df, df, s);
        }
    }

    if (ds2 == 0) {
        #pragma unroll
        for (int q = 0; q < 4; ++q) {
            out[IDX_OFF + n0 + q] = (float)ids[q];
            atomicAdd(&counts[ids[q]], 1);
        }
    }

    __shared__ double red[256];
    red[tid] = (double)s;
    __syncthreads();
    for (int off = 128; off; off >>= 1) {
        if (tid < off) red[tid] += red[tid + off];
        __syncthreads();
    }
    if (tid == 0) atomicAdd(loss_acc, red[0]);
}

__global__ void vq_finalize(const int* __restrict__ counts,
                            const double* __restrict__ loss_acc,
                            float* __restrict__ out)
{
    __shared__ double red[256];
    const int tid = threadIdx.x;
    double s = 0.0;
    for (int k = tid; k < KK; k += 256) {
        const double p = (double)counts[k] / (double)NN;
        s += p * log(p + 1e-10);
    }
    red[tid] = s;
    __syncthreads();
    for (int off = 128; off; off >>= 1) {
        if (tid < off) red[tid] += red[tid + off];
        __syncthreads();
    }
    if (tid == 0) {
        out[PERP_POS] = (float)exp(-red[0]);
        out[LOSS_POS] = (float)(1.25 * loss_acc[0] / (double)QSZ);
    }
}

extern "C" void kernel_launch(void* const* d_in, const int* in_sizes, int n_in,
                              void* d_out, int out_size, void* d_ws, size_t ws_size,
                              hipStream_t stream) {
    const float* x   = (const float*)d_in[0];   // [16,256,4096]
    const float* emb = (const float*)d_in[1];   // [1024,256]
    float* out = (float*)d_out;
    char*  ws  = (char*)d_ws;

    float*     ne        = (float*)(ws + WS_NE);
    int*       idx       = (int*)(ws + WS_IDX);
    int*       counts    = (int*)(ws + WS_CNT);
    double*    loss_acc  = (double*)(ws + WS_LOSS);
    int*       flag_cnt  = (int*)(ws + WS_FLAG);
    _Float16*  eh        = (_Float16*)((char*)d_out + OUT_EH);
    float*     xn        = (float*)((char*)d_out + OUT_XN);
    int*       flag_list = (int*)((char*)d_out + OUT_FL);

    hipMemsetAsync(ws + WS_CNT, 0, KK * 4 + 16, stream);  // counts + loss + flag_cnt

    vq_prep_e<<<KK / 256, 256, 0, stream>>>(emb, ne, eh);
    vq_xnorm<<<NN / 256, 256, 0, stream>>>(x, xn);
    vq_argmin_f16<<<1024, 256, 0, stream>>>(x, eh, ne, xn, idx, flag_cnt, flag_list);
    vq_cleanup<<<256, 512, 0, stream>>>(x, emb, ne, xn, flag_cnt, flag_list, idx);
    vq_gather<<<512, 256, 0, stream>>>(x, emb, idx, out, counts, loss_acc);
    vq_finalize<<<1, 256, 0, stream>>>(counts, loss_acc, out);
}

// Round 9
// 364.617 us; speedup vs baseline: 2.3472x; 2.3472x over previous
//
#include <hip/hip_runtime.h>
#include <math.h>

#define DD 256
#define KK 1024
#define TT 4096
#define BB 16
#define NN (BB*TT)            // 65536
#define QSZ (BB*DD*TT)        // 16777216
#define LOSS_POS QSZ
#define IDX_OFF (QSZ+1)
#define PERP_POS (QSZ+1+NN)

// ws layout
#define WS_NE    0                   // K f32
#define WS_IDX   4096                // N int
#define WS_CNT   (4096 + NN*4)       // K int    (zeroed)
#define WS_LOSS  (WS_CNT + KK*4)     // double   (zeroed)
#define WS_FLAG  (WS_LOSS + 8)       // int      (zeroed)

// scratch carved out of q_out region (consumed before vq_gather overwrites)
#define OUT_EH   0                   // K*D fp16 (512 KB)
#define OUT_XN   (1u<<20)            // N f32    (256 KB)
#define OUT_FL   (2u<<20)            // N int    (256 KB)

#define THR 1.4e-4f

typedef __attribute__((ext_vector_type(8))) _Float16 half8v;
typedef __attribute__((ext_vector_type(4))) float f32x4;

#define GLOAD16(gp, lp) __builtin_amdgcn_global_load_lds( \
    (const __attribute__((address_space(1))) unsigned int*)(gp), \
    (__attribute__((address_space(3))) unsigned int*)(lp), 16, 0, 0)

__device__ __forceinline__ unsigned mapf(float f) {   // order-preserving f32->u32
    unsigned b = __float_as_uint(f);
    return (b & 0x80000000u) ? ~b : (b | 0x80000000u);
}

// ---- numpy-exact pairwise sum of squares over 256 elements ----
__device__ __forceinline__ float np_pairwise_sq(const float* __restrict__ p,
                                                const long stride) {
    float tot[2];
    #pragma unroll
    for (int h = 0; h < 2; ++h) {
        const float* q = p + (long)h * 128 * stride;
        float r[8];
        #pragma unroll
        for (int j = 0; j < 8; ++j) {
            const float v = q[(long)j * stride];
            r[j] = __fmul_rn(v, v);
        }
        for (int i = 8; i < 128; i += 8) {
            #pragma unroll
            for (int j = 0; j < 8; ++j) {
                const float v = q[(long)(i + j) * stride];
                r[j] = __fadd_rn(r[j], __fmul_rn(v, v));
            }
        }
        tot[h] = __fadd_rn(__fadd_rn(__fadd_rn(r[0], r[1]), __fadd_rn(r[2], r[3])),
                           __fadd_rn(__fadd_rn(r[4], r[5]), __fadd_rn(r[6], r[7])));
    }
    return __fadd_rn(tot[0], tot[1]);
}

// ---------------- prep: ||e||^2 + eh = fp16(1024*e) ----------------
__global__ __launch_bounds__(256) void vq_prep_e(const float* __restrict__ emb,
                                                 float* __restrict__ ne,
                                                 _Float16* __restrict__ eh) {
    const int k = blockIdx.x * 256 + threadIdx.x;
    const float* row = emb + (size_t)k * DD;
    ne[k] = np_pairwise_sq(row, 1);
    _Float16* er = eh + (size_t)k * DD;
    #pragma unroll 4
    for (int c = 0; c < DD / 8; ++c) {
        half8v h;
        #pragma unroll
        for (int j = 0; j < 8; ++j) h[j] = (_Float16)(row[c * 8 + j] * 1024.0f);
        *reinterpret_cast<half8v*>(er + c * 8) = h;
    }
}

// ---------------- ||x||^2 (np-exact) ----------------
__global__ __launch_bounds__(256) void vq_xnorm(const float* __restrict__ x,
                                                float* __restrict__ xn) {
    const int n = blockIdx.x * 256 + threadIdx.x;
    const int b = n >> 12;
    const int t = n & 4095;
    xn[n] = np_pairwise_sq(x + (size_t)b * DD * TT + t, TT);
}

// ---------------- main v3: fp16-MFMA, per-kc 64KB LDS staging ----------------
// grid 512 (t-tile 128). 4 waves x 32 t (2 frags). 8 kc rounds, staggered by bx.
// ALL register arrays statically indexed (rule #20). 2 blocks/CU (LDS 68 KB).
__global__ __launch_bounds__(256) void vq_argmin_f16(
    const float* __restrict__ x,
    const _Float16* __restrict__ eh,
    const float* __restrict__ ne,
    const float* __restrict__ xn,
    int* __restrict__ out_idx,
    int* __restrict__ flag_cnt,
    int* __restrict__ flag_list)
{
    __shared__ __align__(16) _Float16 Elds[128 * 256];   // 64 KB: 128 k x 256 d
    __shared__ float nes[KK];                            // 4 KB

    const int tid = threadIdx.x;
    const int w   = tid >> 6;
    const int l   = tid & 63;
    const int l15 = l & 15;
    const int lg  = l >> 4;
    const int bx  = blockIdx.x;        // 512
    const int b   = bx >> 5;
    const int t0  = (bx & 31) * 128;
    const int tw0 = t0 + w * 32;

    for (int i = tid; i < KK; i += 256) nes[i] = ne[i];

    // B fragments (2 t-frags/wave), fully static indices
    half8v Bf0[8], Bf1[8];
    const float* xb = x + (size_t)b * DD * TT;
    #pragma unroll
    for (int dc = 0; dc < 8; ++dc) {
        const int d0 = dc * 32 + lg * 8;
        half8v u0, u1;
        #pragma unroll
        for (int j = 0; j < 8; ++j) {
            u0[j] = (_Float16)xb[(size_t)(d0 + j) * TT + tw0 + l15];
            u1[j] = (_Float16)xb[(size_t)(d0 + j) * TT + tw0 + 16 + l15];
        }
        Bf0[dc] = u0; Bf1[dc] = u1;
    }
    const float xnv0 = xn[b * TT + tw0 + l15];
    const float xnv1 = xn[b * TT + tw0 + 16 + l15];

    float v1a = 3.4028235e38f, v2a = 3.4028235e38f;
    float v1b = 3.4028235e38f, v2b = 3.4028235e38f;
    int   k1a = 0, k1b = 0;

    // staging geometry: call j, thread tid -> LDS bytes j*4096 + tid*16
    //  = half-index j*2048 + tid*8 = row (j*8 + tid>>5), chunk (tid&31) of 16B.
    // source chunk = physical ^ (row&7); row&7 == tid>>5 for all j.
    const int srow = tid >> 5;               // 0..7
    const int scol = tid & 31;               // 0..31
    const int ssrc = (scol ^ srow) * 8;      // halves
    _Float16* ldsw = Elds + w * 512;         // wave-uniform base (+ j*2048)

    for (int kci = 0; kci < 8; ++kci) {
        const int kc = (kci + bx) & 7;       // stagger across blocks
        const int kb = kc * 128;

        __syncthreads();                     // previous chunk's readers done
        #pragma unroll
        for (int j = 0; j < 16; ++j)
            GLOAD16(eh + (size_t)(kb + j * 8 + srow) * DD + ssrc, ldsw + j * 2048);
        __syncthreads();                     // drains vmcnt -> E chunk ready

        for (int fk = 0; fk < 8; ++fk) {
            const int rowb = (fk * 16 + l15) * 256;
            const int sx   = l15 & 7;
            half8v Af[8];
            #pragma unroll
            for (int dc = 0; dc < 8; ++dc)
                Af[dc] = *(const half8v*)&Elds[rowb + (((dc << 2) | lg) ^ sx) * 8];
            f32x4 a0 = {0.f, 0.f, 0.f, 0.f};
            f32x4 a1 = {0.f, 0.f, 0.f, 0.f};
            #pragma unroll
            for (int dc = 0; dc < 8; ++dc) {
                a0 = __builtin_amdgcn_mfma_f32_16x16x32_f16(Af[dc], Bf0[dc], a0, 0, 0, 0);
                a1 = __builtin_amdgcn_mfma_f32_16x16x32_f16(Af[dc], Bf1[dc], a1, 0, 0, 0);
            }
            const float4 nev = *reinterpret_cast<const float4*>(&nes[kb + fk * 16 + lg * 4]);
            const float nv[4] = {nev.x, nev.y, nev.z, nev.w};
            #pragma unroll
            for (int r = 0; r < 4; ++r) {
                const int kk2 = kb + fk * 16 + lg * 4 + r;
                float sa = __fadd_rn(xnv0, nv[r]);
                float sc = fmaf(-0.001953125f, a0[r], sa);   // dot' = 1024*dot
                float mx = fmaxf(v1a, sc);
                v2a = fminf(v2a, mx);
                bool c = sc < v1a;
                v1a = c ? sc : v1a;  k1a = c ? kk2 : k1a;
                sa = __fadd_rn(xnv1, nv[r]);
                sc = fmaf(-0.001953125f, a1[r], sa);
                mx = fmaxf(v1b, sc);
                v2b = fminf(v2b, mx);
                c = sc < v1b;
                v1b = c ? sc : v1b;  k1b = c ? kk2 : k1b;
            }
        }
    }

    // cross-lane merge over lg groups (k-partition), then write + flag
    float v1f[2] = {v1a, v1b};
    float v2f[2] = {v2a, v2b};
    int   k1f[2] = {k1a, k1b};
    #pragma unroll
    for (int ft = 0; ft < 2; ++ft) {
        #pragma unroll
        for (int m = 16; m <= 32; m <<= 1) {
            const float ov1 = __shfl_xor(v1f[ft], m);
            const float ov2 = __shfl_xor(v2f[ft], m);
            const int   ok1 = __shfl_xor(k1f[ft], m);
            const float mx  = fmaxf(v1f[ft], ov1);
            v2f[ft] = fminf(fminf(v2f[ft], ov2), mx);
            const bool take = (ov1 < v1f[ft]) || (ov1 == v1f[ft] && ok1 < k1f[ft]);
            v1f[ft] = take ? ov1 : v1f[ft];
            k1f[ft] = take ? ok1 : k1f[ft];
        }
        if (l < 16) {
            const int n = b * TT + tw0 + ft * 16 + l15;
            out_idx[n] = k1f[ft];
            if (v2f[ft] - v1f[ft] <= THR) {
                const int p = atomicAdd(flag_cnt, 1);
                flag_list[p] = n;
            }
        }
    }
}

// ---------------- cleanup: exact fp32 rescore of flagged rows ----------------
#define CR 16
__global__ __launch_bounds__(512) void vq_cleanup(
    const float* __restrict__ x, const float* __restrict__ emb,
    const float* __restrict__ ne, const float* __restrict__ xn,
    const int* __restrict__ flag_cnt, const int* __restrict__ flag_list,
    int* __restrict__ out_idx)
{
    __shared__ float xr[CR][DD + 4];
    __shared__ float xns_s[CR];
    __shared__ int rowid[CR];
    __shared__ unsigned long long wred[8][8];

    const int tid = threadIdx.x;
    const int wv  = tid >> 6, l = tid & 63;
    const int kt  = tid & 255;
    const int rt  = tid >> 8;
    const int cnt = *flag_cnt;

    for (int base = blockIdx.x * CR; base < cnt; base += gridDim.x * CR) {
        const int nr = min(CR, cnt - base);
        __syncthreads();
        if (tid < CR) {
            const int n = flag_list[base + ((tid < nr) ? tid : (nr - 1))];
            rowid[tid] = n;
            xns_s[tid] = xn[n];
        }
        __syncthreads();
        {
            const int r = tid >> 5, d0 = (tid & 31) * 8;
            const int n = rowid[r], bb2 = n >> 12, t = n & 4095;
            const float* xc = x + (size_t)bb2 * DD * TT + t;
            #pragma unroll
            for (int q = 0; q < 8; ++q) xr[r][d0 + q] = xc[(size_t)(d0 + q) * TT];
        }
        __syncthreads();

        const int k0 = kt * 4;
        float acc4[4][8];
        #pragma unroll
        for (int a = 0; a < 4; ++a)
            #pragma unroll
            for (int r = 0; r < 8; ++r) acc4[a][r] = 0.f;

        for (int ch = 0; ch < DD / 8; ++ch) {
            const int d0 = ch * 8;
            float xc8[8][8];
            #pragma unroll
            for (int r = 0; r < 8; ++r) {
                const float4 xa = *reinterpret_cast<const float4*>(&xr[rt * 8 + r][d0]);
                const float4 xbv = *reinterpret_cast<const float4*>(&xr[rt * 8 + r][d0 + 4]);
                xc8[r][0] = xa.x;  xc8[r][1] = xa.y;  xc8[r][2] = xa.z;  xc8[r][3] = xa.w;
                xc8[r][4] = xbv.x; xc8[r][5] = xbv.y; xc8[r][6] = xbv.z; xc8[r][7] = xbv.w;
            }
            #pragma unroll
            for (int a = 0; a < 4; ++a) {
                const float* er = emb + (size_t)(k0 + a) * DD + d0;
                const float4 ea = *reinterpret_cast<const float4*>(er);
                const float4 eb2 = *reinterpret_cast<const float4*>(er + 4);
                const float ev[8] = {ea.x, ea.y, ea.z, ea.w, eb2.x, eb2.y, eb2.z, eb2.w};
                #pragma unroll
                for (int q = 0; q < 8; ++q)
                    #pragma unroll
                    for (int r = 0; r < 8; ++r)
                        acc4[a][r] = fmaf(ev[q], xc8[r][q], acc4[a][r]);
            }
        }

        #pragma unroll
        for (int r = 0; r < 8; ++r) {
            const float xnv2 = xns_s[rt * 8 + r];
            unsigned long long bb3 = ~0ull;
            #pragma unroll
            for (int a = 0; a < 4; ++a) {
                const float s1 = __fadd_rn(xnv2, ne[k0 + a]);
                const float sc = __fsub_rn(s1, __fmul_rn(2.0f, acc4[a][r]));
                const unsigned long long pkk =
                    ((unsigned long long)mapf(sc) << 32) | (unsigned)(k0 + a);
                bb3 = (pkk < bb3) ? pkk : bb3;
            }
            unsigned long long v = bb3;
            #pragma unroll
            for (int m = 1; m < 64; m <<= 1) {
                const unsigned long long o = __shfl_xor(v, m);
                v = (o < v) ? o : v;
            }
            if (l == 0) wred[wv][r] = v;
        }
        __syncthreads();
        if (wv == 0) {
            const int row = l >> 2, sw = l & 3;
            const int srcw = (row < 8) ? sw : (4 + sw);
            unsigned long long v = wred[srcw][row & 7];
            #pragma unroll
            for (int m = 1; m < 4; m <<= 1) {
                const unsigned long long o = __shfl_xor(v, m);
                v = (o < v) ? o : v;
            }
            if (sw == 0 && row < nr) out_idx[rowid[row]] = (int)(v & 0xFFFFFFFFu);
        }
    }
}

// ---------------- gather (16B/lane) + loss + counts ----------------
__global__ __launch_bounds__(256) void vq_gather(
    const float* __restrict__ x, const float* __restrict__ emb,
    const int* __restrict__ idx, float* __restrict__ out,
    int* __restrict__ counts, double* __restrict__ loss_acc)
{
    const int tid = threadIdx.x;
    const int bid = blockIdx.x;
    const int ds2 = bid & 7;
    const int g   = (bid >> 3) * 256 + tid;    // 0..16383
    const int b   = g >> 10;
    const int t0q = (g & 1023) * 4;
    const int n0  = b * TT + t0q;

    int ids[4];
    #pragma unroll
    for (int q = 0; q < 4; ++q) ids[q] = idx[n0 + q];

    const int dbase = ds2 * 32;
    const float* xb = x + (size_t)b * DD * TT;
    float* ob       = out + (size_t)b * DD * TT;

    float s = 0.f;
    for (int d4 = 0; d4 < 8; ++d4) {
        const int d = dbase + d4 * 4;
        float ea[4][4];
        #pragma unroll
        for (int q = 0; q < 4; ++q) {
            const float4 v = *reinterpret_cast<const float4*>(emb + (size_t)ids[q] * DD + d);
            ea[q][0] = v.x; ea[q][1] = v.y; ea[q][2] = v.z; ea[q][3] = v.w;
        }
        #pragma unroll
        for (int di = 0; di < 4; ++di) {
            const float4 xv = *reinterpret_cast<const float4*>(xb + (size_t)(d + di) * TT + t0q);
            float4 ov;
            ov.x = ea[0][di]; ov.y = ea[1][di]; ov.z = ea[2][di]; ov.w = ea[3][di];
            *reinterpret_cast<float4*>(ob + (size_t)(d + di) * TT + t0q) = ov;
            float df;
            df = ov.x - xv.x; s = fmaf(df, df, s);
            df = ov.y - xv.y; s = fmaf(df, df, s);
            df = ov.z - xv.z; s = fmaf(df, df, s);
            df = ov.w - xv.w; s = fmaf(df, df, s);
        }
    }

    if (ds2 == 0) {
        #pragma unroll
        for (int q = 0; q < 4; ++q) {
            out[IDX_OFF + n0 + q] = (float)ids[q];
            atomicAdd(&counts[ids[q]], 1);
        }
    }

    __shared__ double red[256];
    red[tid] = (double)s;
    __syncthreads();
    for (int off = 128; off; off >>= 1) {
        if (tid < off) red[tid] += red[tid + off];
        __syncthreads();
    }
    if (tid == 0) atomicAdd(loss_acc, red[0]);
}

__global__ void vq_finalize(const int* __restrict__ counts,
                            const double* __restrict__ loss_acc,
                            float* __restrict__ out)
{
    __shared__ double red[256];
    const int tid = threadIdx.x;
    double s = 0.0;
    for (int k = tid; k < KK; k += 256) {
        const double p = (double)counts[k] / (double)NN;
        s += p * log(p + 1e-10);
    }
    red[tid] = s;
    __syncthreads();
    for (int off = 128; off; off >>= 1) {
        if (tid < off) red[tid] += red[tid + off];
        __syncthreads();
    }
    if (tid == 0) {
        out[PERP_POS] = (float)exp(-red[0]);
        out[LOSS_POS] = (float)(1.25 * loss_acc[0] / (double)QSZ);
    }
}

extern "C" void kernel_launch(void* const* d_in, const int* in_sizes, int n_in,
                              void* d_out, int out_size, void* d_ws, size_t ws_size,
                              hipStream_t stream) {
    const float* x   = (const float*)d_in[0];   // [16,256,4096]
    const float* emb = (const float*)d_in[1];   // [1024,256]
    float* out = (float*)d_out;
    char*  ws  = (char*)d_ws;

    float*     ne        = (float*)(ws + WS_NE);
    int*       idx       = (int*)(ws + WS_IDX);
    int*       counts    = (int*)(ws + WS_CNT);
    double*    loss_acc  = (double*)(ws + WS_LOSS);
    int*       flag_cnt  = (int*)(ws + WS_FLAG);
    _Float16*  eh        = (_Float16*)((char*)d_out + OUT_EH);
    float*     xn        = (float*)((char*)d_out + OUT_XN);
    int*       flag_list = (int*)((char*)d_out + OUT_FL);

    hipMemsetAsync(ws + WS_CNT, 0, KK * 4 + 16, stream);  // counts + loss + flag_cnt

    vq_prep_e<<<KK / 256, 256, 0, stream>>>(emb, ne, eh);
    vq_xnorm<<<NN / 256, 256, 0, stream>>>(x, xn);
    vq_argmin_f16<<<512, 256, 0, stream>>>(x, eh, ne, xn, idx, flag_cnt, flag_list);
    vq_cleanup<<<256, 512, 0, stream>>>(x, emb, ne, xn, flag_cnt, flag_list, idx);
    vq_gather<<<512, 256, 0, stream>>>(x, emb, idx, out, counts, loss_acc);
    vq_finalize<<<1, 256, 0, stream>>>(counts, loss_acc, out);
}